// Round 6
// baseline (158.602 us; speedup 1.0000x reference)
//
#include <hip/hip_runtime.h>
#include <stdint.h>

// Problem constants
//  B = 32768 samples, T_X = 4, K = 128, 64 groups x 512, out = (64,128,1,1024) fp32
typedef __attribute__((ext_vector_type(8))) short bf16x8;  // 8 bf16 in 4 VGPRs
typedef __attribute__((ext_vector_type(4))) float f32x4;

__device__ __forceinline__ unsigned short f2bf(float x) {
    union { float f; uint32_t u; } v; v.f = x;
    uint32_t r = v.u + 0x7FFFu + ((v.u >> 16) & 1u);   // RNE
    return (unsigned short)(r >> 16);
}
// v_cvt_pk_bf16_f32: dst.lo=bf16(a), dst.hi=bf16(b), RNE (passed r10/r11).
__device__ __forceinline__ uint32_t cvtpk(float a, float b) {
    uint32_t r;
    asm("v_cvt_pk_bf16_f32 %0, %1, %2" : "=v"(r) : "v"(a), "v"(b));
    return r;
}
__device__ __forceinline__ float bf2f(uint32_t lo) {
    union { uint32_t u; float f; } v; v.u = lo << 16; return v.f;
}
__device__ __forceinline__ float lrelu(float v) { return v > 0.f ? v : 0.01f * v; }

// async global->LDS DMA, 16 B per lane; LDS dest = wave-uniform base + lane*16
__device__ __forceinline__ void gload_lds16(const void* g, void* l) {
    __builtin_amdgcn_global_load_lds(
        (const __attribute__((address_space(1))) uint32_t*)g,
        (__attribute__((address_space(3))) uint32_t*)l, 16, 0, 0);
}

// ---------------------------------------------------------------------------
// K0: precompute (LDS-tiled small GEMMs) — unchanged, proven
// ---------------------------------------------------------------------------
__global__ __launch_bounds__(256) void precompute_kernel(
    const float* __restrict__ Wq, const float* __restrict__ Wk,
    const float* __restrict__ Wv, const float* __restrict__ conv_w,
    const float* __restrict__ conv_b, const float* __restrict__ bn_gamma,
    const float* __restrict__ bn_beta, const float* __restrict__ bn_mean,
    const float* __restrict__ bn_var,
    unsigned short* __restrict__ Gh, unsigned short* __restrict__ Gl,
    unsigned short* __restrict__ Mh,
    float* __restrict__ scale2, float* __restrict__ bias2)
{
    __shared__ float lds0[2176];
    __shared__ float lds1[2176];
    const int tid = threadIdx.x;
    const int bid = blockIdx.x;

    if (bid == 192) {
        if (tid < 128) {
            float sc = bn_gamma[tid] * rsqrtf(bn_var[tid] + 1e-5f);
            scale2[tid] = sc;
            bias2[tid]  = (conv_b[tid] - bn_mean[tid]) * sc + bn_beta[tid];
        }
        return;
    }

    if (bid < 64) {                                // ---- G tile (i0, j0)
        int i0 = (bid >> 3) << 4, j0 = (bid & 7) << 4;
        #pragma unroll
        for (int t = 0; t < 8; ++t) {
            int e = tid + t * 256;
            int o = e >> 4, c = e & 15;
            lds0[o * 17 + c] = Wk[o * 128 + i0 + c];
            lds1[o * 17 + c] = Wq[o * 128 + j0 + c];
        }
        __syncthreads();
        int ti = tid >> 4, tj = tid & 15;
        float sum = 0.f;
        #pragma unroll 8
        for (int o = 0; o < 128; ++o) sum += lds0[o * 17 + ti] * lds1[o * 17 + tj];
        float val = sum * 0.08838834764831845f;    // 1/sqrt(128)
        unsigned short h = f2bf(val);
        int idx = (i0 + ti) * 128 + j0 + tj;
        Gh[idx] = h;
        Gl[idx] = f2bf(val - bf2f(h));
    } else {                                       // ---- M tile (o0, c0)
        int rel = bid - 64;
        int o0 = (rel >> 4) << 4, c0 = (rel & 15) << 4;
        int cw0 = (c0 >> 7) << 7, cc0 = c0 & 127;
        #pragma unroll
        for (int t = 0; t < 8; ++t) {
            int e = tid + t * 256;
            int to = e >> 7, k = e & 127;
            lds0[to * 132 + k] = conv_w[(o0 + to) * 256 + cw0 + k];
            int kk = e >> 4, c = e & 15;
            lds1[kk * 17 + c] = Wv[kk * 128 + cc0 + c];
        }
        __syncthreads();
        int to = tid >> 4, tc = tid & 15;
        float sum = 0.f;
        #pragma unroll 8
        for (int k = 0; k < 128; ++k) sum += lds0[to * 132 + k] * lds1[k * 17 + tc];
        Mh[(o0 + to) * 256 + c0 + tc] = f2bf(sum * 0.7071067811865476f);
    }
}

#define AADDR(row, gi)   (((row) << 8) + ((((gi) ^ ((row) & 7))) << 4))

// ---------------------------------------------------------------------------
// K1 (r12): 16 samples/block, 2048 blocks, 48 KB LDS, x via global_load_lds.
// r6-r11 established: the compiler never holds X (64 regs) across barriers
// -> every register-path x read is latency-exposed and stuck at 1.8-3 TB/s.
// Fix: x -> LDS by DMA (no VGPR dest, nothing to sink). 48 KB LDS -> 3
// blocks/CU -> ~120 KB DMA in flight per CU (full-BW queue depth).
// Schedule (in-order vmcnt respected by construction):
//   entry:  y loads -> G prefetch (regs)           [vmem: y, G]
//   0a:     pack y -> LDS (waits y only)
//   bar1:   drains y+G only (DMA not yet issued)
//   DMA:    8x gload_lds per wave (x tile, swizzled source)
//   0b:     g = Y@G^T from regs+LDS only (lgkmcnt; never waits x)
//   bar2:   drains x DMA (overlapped with 0b + cross-block stagger)
//   ph1:    x from LDS (swizzled reads), dot+softmax+U-build (cvtpk)
//   bar3 -> ph2: Z = U@M^T -> epilogue
// LDS map: [0,32K) x fp32 (16 x 2KB, granule-swizzled)
//          [32K,36K) y-hi / [36K,40K) y-lo  -> ph1+: U-low  [32K,40K)
//          [40K,48K) gbuf fp32 (16x128)     -> ph1+: U-high [40K,48K)
// (U-high rows 2b,2b+1 = exactly the gbuf row b the same thread just read.)
// x swizzle (both sides, involution): u = p ^ ((p>>2)&6) ^ ((s&3)<<1).
// ---------------------------------------------------------------------------
__global__ __launch_bounds__(256)
__attribute__((amdgpu_waves_per_eu(3)))
void fused_kernel(
    const float* __restrict__ x, const float* __restrict__ y,
    const unsigned short* __restrict__ Gh, const unsigned short* __restrict__ Gl,
    const unsigned short* __restrict__ Mh,
    const float* __restrict__ scale2, const float* __restrict__ bias2,
    float* __restrict__ out)
{
    __shared__ __align__(16) unsigned char smem[49152];
    float* gbufF = (float*)(smem + 40960);

    const int tid = threadIdx.x;
    const int w = tid >> 6;          // wave 0..3
    const int l = tid & 63;          // lane
    const int quad = l >> 4;
    const int i16 = l & 15;
    const int bid = blockIdx.x;
    const int b0 = bid * 16;
    const int b_loc = 4 * w + quad;  // this thread's sample

    // ---- (1) y loads (consumed in 0a)
    const int row = tid >> 4, gk = tid & 15;    // 256 granules: 16 rows x 16
    const float* yb = y + (size_t)(b0 + row) * 128 + gk * 8;
    float4 yv0 = *(const float4*)(yb);
    float4 yv1 = *(const float4*)(yb + 4);

    // ---- (2) all G B-frags to registers (consumed in 0b; issued BEFORE the
    // x DMA so 0b's waits never include x)
    bf16x8 pgh[4][2], pgl[4][2];
    #pragma unroll
    for (int ks = 0; ks < 4; ++ks) {
        int ksr = (ks + bid) & 3;              // per-block rotation
        #pragma unroll
        for (int n = 0; n < 2; ++n) {
            int off = ((2 * w + n) * 16 + i16) * 128 + ksr * 32 + quad * 8;
            pgh[ks][n] = *(const bf16x8*)(Gh + off);
            pgl[ks][n] = *(const bf16x8*)(Gl + off);
        }
    }

    // ---- Phase 0a: pack y (split bf16 hi/lo) into MFMA-A-frag layout
    {
        float f[8] = {yv0.x, yv0.y, yv0.z, yv0.w, yv1.x, yv1.y, yv1.z, yv1.w};
        uint32_t hi[4], lo[4];
        #pragma unroll
        for (int e = 0; e < 4; ++e) {
            unsigned short h0 = f2bf(f[2 * e]), h1 = f2bf(f[2 * e + 1]);
            hi[e] = (uint32_t)h0 | ((uint32_t)h1 << 16);
            lo[e] = (uint32_t)f2bf(f[2 * e] - bf2f(h0)) |
                    ((uint32_t)f2bf(f[2 * e + 1] - bf2f(h1)) << 16);
        }
        int addr = AADDR(row, gk);             // rows 0..15 -> [0,4K)
        *(uint4*)(smem + 32768 + addr) = make_uint4(hi[0], hi[1], hi[2], hi[3]);
        *(uint4*)(smem + 36864 + addr) = make_uint4(lo[0], lo[1], lo[2], lo[3]);
    }
    __syncthreads();   // bar1: drains y+G only (x DMA not yet issued)

    // ---- x DMA: 32 KB tile, 8 chunks of 1024 B per wave. LDS dest linear;
    // source pre-swizzled so reads can use the conflict-reducing layout.
    #pragma unroll
    for (int k = 0; k < 8; ++k) {
        int c  = w * 8 + k;                    // chunk 0..31
        int s  = c >> 1, hf = c & 1;           // sample, half
        int p  = hf * 64 + l;                  // LDS granule within sample
        int u  = p ^ ((p >> 2) & 6) ^ ((s & 3) << 1);   // involution
        const float* src = x + (size_t)(b0 + s) * 512 + u * 4;
        gload_lds16(src, smem + s * 2048 + hf * 1024);
    }

    // ---- Phase 0b: g = Y @ G^T (split precision); registers + LDS only.
    {
        f32x4 accg[2];
        accg[0] = (f32x4){0.f, 0.f, 0.f, 0.f};
        accg[1] = (f32x4){0.f, 0.f, 0.f, 0.f};
        #pragma unroll
        for (int ks = 0; ks < 4; ++ks) {
            int ksr = (ks + bid) & 3;
            int aaddr = AADDR(i16, ksr * 4 + quad);
            bf16x8 ah = *(const bf16x8*)(smem + 32768 + aaddr);
            bf16x8 al = *(const bf16x8*)(smem + 36864 + aaddr);
            #pragma unroll
            for (int n = 0; n < 2; ++n) {
                accg[n] = __builtin_amdgcn_mfma_f32_16x16x32_bf16(ah, pgh[ks][n], accg[n], 0, 0, 0);
                accg[n] = __builtin_amdgcn_mfma_f32_16x16x32_bf16(al, pgh[ks][n], accg[n], 0, 0, 0);
                accg[n] = __builtin_amdgcn_mfma_f32_16x16x32_bf16(ah, pgl[ks][n], accg[n], 0, 0, 0);
            }
        }
        // C-frag: col = i16, row = quad*4+r -> gbuf fp32
        #pragma unroll
        for (int n = 0; n < 2; ++n) {
            int i = (2 * w + n) * 16 + i16;
            #pragma unroll
            for (int r = 0; r < 4; ++r)
                gbufF[(quad * 4 + r) * 128 + i] = accg[n][r];
        }
    }
    __syncthreads();   // bar2: drains the x DMA (overlapped with 0b)

    // ---- Phase 1: dot + softmax + U build; x from LDS (swizzled reads).
    {
        float4 ga = *(const float4*)(gbufF + b_loc * 128 + i16 * 8);
        float4 gb = *(const float4*)(gbufF + b_loc * 128 + i16 * 8 + 4);
        float xf[4][8];
        float p[4];
        #pragma unroll
        for (int t = 0; t < 4; ++t) {
            int g0 = t * 32 + i16 * 2;
            int q  = g0 ^ ((g0 >> 2) & 6) ^ ((b_loc & 3) << 1);
            const float* xp = (const float*)(smem + b_loc * 2048 + q * 16);
            float4 a = *(const float4*)xp;
            float4 b = *(const float4*)(xp + 4);
            xf[t][0] = a.x; xf[t][1] = a.y; xf[t][2] = a.z; xf[t][3] = a.w;
            xf[t][4] = b.x; xf[t][5] = b.y; xf[t][6] = b.z; xf[t][7] = b.w;
            p[t] = a.x * ga.x + a.y * ga.y + a.z * ga.z + a.w * ga.w
                 + b.x * gb.x + b.y * gb.y + b.z * gb.z + b.w * gb.w;
        }
        #pragma unroll
        for (int off = 8; off >= 1; off >>= 1) {
            p[0] += __shfl_xor(p[0], off);
            p[1] += __shfl_xor(p[1], off);
            p[2] += __shfl_xor(p[2], off);
            p[3] += __shfl_xor(p[3], off);
        }
        float mx = fmaxf(fmaxf(p[0], p[1]), fmaxf(p[2], p[3]));
        float e0 = __expf(p[0] - mx), e1 = __expf(p[1] - mx);
        float e2 = __expf(p[2] - mx), e3 = __expf(p[3] - mx);
        float inv = 1.f / (e0 + e1 + e2 + e3);
        float w0 = e0 * inv, w1 = e1 * inv, w2 = e2 * inv, w3 = e3 * inv;
        int r0 = 2 * b_loc;
        int a0 = AADDR(r0, i16), a1 = AADDR(r0 + 1, i16);
        uint32_t eL[4], oL[4], eH[4], oH[4];
        #pragma unroll
        for (int e = 0; e < 4; ++e) {
            int c0 = 2 * e, c1 = 2 * e + 1;
            eL[e] = cvtpk(w0 * xf[0][c0] + w1 * xf[1][c0], w0 * xf[0][c1] + w1 * xf[1][c1]);
            oL[e] = cvtpk(w0 * xf[0][c0] - w1 * xf[1][c0], w0 * xf[0][c1] - w1 * xf[1][c1]);
            eH[e] = cvtpk(w2 * xf[2][c0] + w3 * xf[3][c0], w2 * xf[2][c1] + w3 * xf[3][c1]);
            oH[e] = cvtpk(w2 * xf[2][c0] - w3 * xf[3][c0], w2 * xf[2][c1] - w3 * xf[3][c1]);
        }
        *(uint4*)(smem + 32768 + a0) = make_uint4(eL[0], eL[1], eL[2], eL[3]);
        *(uint4*)(smem + 32768 + a1) = make_uint4(oL[0], oL[1], oL[2], oL[3]);
        *(uint4*)(smem + 40960 + a0) = make_uint4(eH[0], eH[1], eH[2], eH[3]);
        *(uint4*)(smem + 40960 + a1) = make_uint4(oH[0], oH[1], oH[2], oH[3]);
    }

    // Prefetch phase-2 first-ks B-frags before the barrier (L2-resident)
    const int ks0b = bid & 7;
    bf16x8 pmh[2];
    {
        int half = ks0b >> 2, kk = ks0b & 3;
        #pragma unroll
        for (int n = 0; n < 2; ++n)
            pmh[n] = *(const bf16x8*)(Mh + ((2 * w + n) * 16 + i16) * 256 + half * 128 + kk * 32 + quad * 8);
    }
    __syncthreads();   // bar3: phase 2 reads all waves' U rows

    // ---- Phase 2: Z = U(32x256) @ M^T, column-split waves
    f32x4 acc[2][2];
    #pragma unroll
    for (int rb = 0; rb < 2; ++rb)
        #pragma unroll
        for (int n = 0; n < 2; ++n) acc[rb][n] = (f32x4){0.f, 0.f, 0.f, 0.f};

    #pragma unroll
    for (int ks = 0; ks < 8; ++ks) {
        int ksr = (ks + bid) & 7;
        int half = ksr >> 2, kk = ksr & 3;
        int base = 32768 + (half << 13);           // U-low 32768 / U-high 40960
        int gi = kk * 4 + quad;
        bf16x8 a0v = *(const bf16x8*)(smem + base + AADDR(i16, gi));
        bf16x8 a1v = *(const bf16x8*)(smem + base + AADDR(16 + i16, gi));
        #pragma unroll
        for (int n = 0; n < 2; ++n) {
            bf16x8 bh;
            if (ks == 0) bh = pmh[n];
            else bh = *(const bf16x8*)(Mh + ((2 * w + n) * 16 + i16) * 256 + half * 128 + kk * 32 + quad * 8);
            acc[0][n] = __builtin_amdgcn_mfma_f32_16x16x32_bf16(a0v, bh, acc[0][n], 0, 0, 0);
            acc[1][n] = __builtin_amdgcn_mfma_f32_16x16x32_bf16(a1v, bh, acc[1][n], 0, 0, 0);
        }
    }

    // ---- Epilogue: scale/bias/LeakyReLU, j-contiguous float4 stores.
    {
        float* outp = out + (size_t)(bid >> 5) * 131072 + (bid & 31) * 32;
        #pragma unroll
        for (int n = 0; n < 2; ++n) {
            int o = (2 * w + n) * 16 + i16;
            float sc = scale2[o], bi = bias2[o];
            #pragma unroll
            for (int rb = 0; rb < 2; ++rb) {
                int jb = 16 * rb + quad * 4;
                f32x4 a = acc[rb][n];
                float4 r;
                r.x = lrelu(a[0] * sc + bi);
                r.y = lrelu(a[1] * sc + bi);
                r.z = lrelu(a[2] * sc + bi);
                r.w = lrelu(a[3] * sc + bi);
                *(float4*)(outp + (size_t)o * 1024 + jb) = r;
            }
        }
    }
}

extern "C" void kernel_launch(void* const* d_in, const int* in_sizes, int n_in,
                              void* d_out, int out_size, void* d_ws, size_t ws_size,
                              hipStream_t stream)
{
    (void)in_sizes; (void)n_in; (void)out_size; (void)ws_size;
    const float* x        = (const float*)d_in[0];
    const float* y        = (const float*)d_in[1];
    const float* Wq       = (const float*)d_in[2];
    const float* Wk       = (const float*)d_in[3];
    const float* Wv       = (const float*)d_in[4];
    const float* conv_w   = (const float*)d_in[5];
    const float* conv_b   = (const float*)d_in[6];
    const float* bn_gamma = (const float*)d_in[7];
    const float* bn_beta  = (const float*)d_in[8];
    const float* bn_mean  = (const float*)d_in[9];
    const float* bn_var   = (const float*)d_in[10];

    unsigned char* ws = (unsigned char*)d_ws;
    unsigned short* Gh = (unsigned short*)(ws);                // 32 KB
    unsigned short* Gl = (unsigned short*)(ws + 32768);        // 32 KB
    unsigned short* Mh = (unsigned short*)(ws + 65536);        // 64 KB
    float* scale2      = (float*)(ws + 131072);                // 512 B
    float* bias2       = (float*)(ws + 131584);                // 512 B

    hipLaunchKernelGGL(precompute_kernel, dim3(193), dim3(256), 0, stream,
                       Wq, Wk, Wv, conv_w, conv_b, bn_gamma, bn_beta, bn_mean,
                       bn_var, Gh, Gl, Mh, scale2, bias2);
    hipLaunchKernelGGL(fused_kernel, dim3(2048), dim3(256), 0, stream,
                       x, y, Gh, Gl, Mh, scale2, bias2, (float*)d_out);
}

// Round 7
// 153.317 us; speedup vs baseline: 1.0345x; 1.0345x over previous
//
#include <hip/hip_runtime.h>
#include <stdint.h>

// Problem constants
//  B = 32768 samples, T_X = 4, K = 128, 64 groups x 512, out = (64,128,1,1024) fp32
typedef __attribute__((ext_vector_type(8))) short bf16x8;  // 8 bf16 in 4 VGPRs
typedef __attribute__((ext_vector_type(4))) float f32x4;

__device__ __forceinline__ unsigned short f2bf(float x) {
    union { float f; uint32_t u; } v; v.f = x;
    uint32_t r = v.u + 0x7FFFu + ((v.u >> 16) & 1u);   // RNE
    return (unsigned short)(r >> 16);
}
// v_cvt_pk_bf16_f32: dst.lo=bf16(a), dst.hi=bf16(b), RNE (passed r10-r12).
__device__ __forceinline__ uint32_t cvtpk(float a, float b) {
    uint32_t r;
    asm("v_cvt_pk_bf16_f32 %0, %1, %2" : "=v"(r) : "v"(a), "v"(b));
    return r;
}
__device__ __forceinline__ float bf2f(uint32_t lo) {
    union { uint32_t u; float f; } v; v.u = lo << 16; return v.f;
}
__device__ __forceinline__ float lrelu(float v) { return v > 0.f ? v : 0.01f * v; }

// Pinned global loads: asm volatile cannot be sunk by the scheduler (the fix
// for r6/r8/r10 where VGPR_Count=84 proved the X-hoist was silently dropped).
// "memory" clobber keeps compiler-emitted loads from migrating into the
// counted-vmcnt window; "=&v" early-clobber (dest != addr pair).
__device__ __forceinline__ f32x4 ald4(const float* p) {
    f32x4 d;
    asm volatile("global_load_dwordx4 %0, %1, off" : "=&v"(d) : "v"(p) : "memory");
    return d;
}
__device__ __forceinline__ bf16x8 bld8(const unsigned short* p) {
    bf16x8 d;
    asm volatile("global_load_dwordx4 %0, %1, off" : "=&v"(d) : "v"(p) : "memory");
    return d;
}
// Counted VMEM wait (T4) + sched fence (rule #18: consumers must not hoist
// above the wait).
#define WAITV(N) do { asm volatile("s_waitcnt vmcnt(" #N ")" ::: "memory"); \
                      __builtin_amdgcn_sched_barrier(0); } while (0)
// Raw barrier: LDS drained (lgkmcnt only), VMEM queue NOT drained — the
// compiler's __syncthreads would emit vmcnt(0) and kill the pipeline.
#define BARRIER() do { asm volatile("s_waitcnt lgkmcnt(0)\n\ts_barrier" ::: "memory"); \
                       __builtin_amdgcn_sched_barrier(0); } while (0)

// ---------------------------------------------------------------------------
// K0: precompute (LDS-tiled small GEMMs) — unchanged, proven
// ---------------------------------------------------------------------------
__global__ __launch_bounds__(256) void precompute_kernel(
    const float* __restrict__ Wq, const float* __restrict__ Wk,
    const float* __restrict__ Wv, const float* __restrict__ conv_w,
    const float* __restrict__ conv_b, const float* __restrict__ bn_gamma,
    const float* __restrict__ bn_beta, const float* __restrict__ bn_mean,
    const float* __restrict__ bn_var,
    unsigned short* __restrict__ Gh, unsigned short* __restrict__ Gl,
    unsigned short* __restrict__ Mh,
    float* __restrict__ scale2, float* __restrict__ bias2)
{
    __shared__ float lds0[2176];
    __shared__ float lds1[2176];
    const int tid = threadIdx.x;
    const int bid = blockIdx.x;

    if (bid == 192) {
        if (tid < 128) {
            float sc = bn_gamma[tid] * rsqrtf(bn_var[tid] + 1e-5f);
            scale2[tid] = sc;
            bias2[tid]  = (conv_b[tid] - bn_mean[tid]) * sc + bn_beta[tid];
        }
        return;
    }

    if (bid < 64) {                                // ---- G tile (i0, j0)
        int i0 = (bid >> 3) << 4, j0 = (bid & 7) << 4;
        #pragma unroll
        for (int t = 0; t < 8; ++t) {
            int e = tid + t * 256;
            int o = e >> 4, c = e & 15;
            lds0[o * 17 + c] = Wk[o * 128 + i0 + c];
            lds1[o * 17 + c] = Wq[o * 128 + j0 + c];
        }
        __syncthreads();
        int ti = tid >> 4, tj = tid & 15;
        float sum = 0.f;
        #pragma unroll 8
        for (int o = 0; o < 128; ++o) sum += lds0[o * 17 + ti] * lds1[o * 17 + tj];
        float val = sum * 0.08838834764831845f;    // 1/sqrt(128)
        unsigned short h = f2bf(val);
        int idx = (i0 + ti) * 128 + j0 + tj;
        Gh[idx] = h;
        Gl[idx] = f2bf(val - bf2f(h));
    } else {                                       // ---- M tile (o0, c0)
        int rel = bid - 64;
        int o0 = (rel >> 4) << 4, c0 = (rel & 15) << 4;
        int cw0 = (c0 >> 7) << 7, cc0 = c0 & 127;
        #pragma unroll
        for (int t = 0; t < 8; ++t) {
            int e = tid + t * 256;
            int to = e >> 7, k = e & 127;
            lds0[to * 132 + k] = conv_w[(o0 + to) * 256 + cw0 + k];
            int kk = e >> 4, c = e & 15;
            lds1[kk * 17 + c] = Wv[kk * 128 + cc0 + c];
        }
        __syncthreads();
        int to = tid >> 4, tc = tid & 15;
        float sum = 0.f;
        #pragma unroll 8
        for (int k = 0; k < 128; ++k) sum += lds0[to * 132 + k] * lds1[k * 17 + tc];
        Mh[(o0 + to) * 256 + c0 + tc] = f2bf(sum * 0.7071067811865476f);
    }
}

#define AADDR(row, gi)   (((row) << 8) + ((((gi) ^ ((row) & 7))) << 4))

// ---------------------------------------------------------------------------
// K1 (r13): r10 geometry (32 samples/block, 1024 blocks, 32 KB LDS) with the
// load pipeline taken OUT of the compiler's hands:
//   - ALL entry loads are pinned asm global_load_dwordx4, strict issue order
//     y(2) -> G(16) -> X(16)  (fixed vmcnt queue, cannot be sunk)
//   - raw s_barrier + lgkmcnt(0) only (no compiler vmcnt(0) drains)
//   - counted waits: vmcnt(32) before y-pack, vmcnt(16) before 0b MFMAs,
//     vmcnt(0) only at phase 1 -> the 67 MB x stream drains under 0a/0b and
//     across ~2 resident blocks/CU (~130 KB/CU in flight).
//   - waves_per_eu(2): 256-reg budget; ~136 forced-live VGPRs cannot spill.
// LDS overlays (proven r6/r10 invariants):
//   [0,16K)  phase0: y bf16 hi [0,8K) + lo [8K,16K) -> phase1+: U-low bf16
//   [16K,32K) phase0b out: gbuf fp32 (32x128)       -> phase1+: U-high bf16
// ---------------------------------------------------------------------------
__global__ __launch_bounds__(256)
__attribute__((amdgpu_waves_per_eu(2)))
void fused_kernel(
    const float* __restrict__ x, const float* __restrict__ y,
    const unsigned short* __restrict__ Gh, const unsigned short* __restrict__ Gl,
    const unsigned short* __restrict__ Mh,
    const float* __restrict__ scale2, const float* __restrict__ bias2,
    float* __restrict__ out)
{
    __shared__ __align__(16) unsigned char smem[32768];
    float* gbufF = (float*)(smem + 16384);

    const int tid = threadIdx.x;
    const int w = tid >> 6;          // wave 0..3
    const int l = tid & 63;          // lane
    const int quad = l >> 4;
    const int i16 = l & 15;
    const int bid = blockIdx.x;
    const int b0 = bid * 32;

    // ================= pinned VMEM queue: y(2), G(16), X(16) ==============
    // (1) y — consumed by phase 0a
    int rowA[2], gkA[2];
    f32x4 yv0[2], yv1[2];
    #pragma unroll
    for (int it = 0; it < 2; ++it) {
        int j = tid + it * 256;                // 512 granules: 32 rows x 16
        rowA[it] = j >> 4; gkA[it] = j & 15;
        const float* yb = y + (size_t)(b0 + rowA[it]) * 128 + gkA[it] * 8;
        yv0[it] = ald4(yb);
        yv1[it] = ald4(yb + 4);
    }
    // (2) G B-frags — consumed by phase 0b
    bf16x8 pgh[4][2], pgl[4][2];
    #pragma unroll
    for (int ks = 0; ks < 4; ++ks) {
        int ksr = (ks + bid) & 3;              // per-block rotation
        #pragma unroll
        for (int n = 0; n < 2; ++n) {
            int off = ((2 * w + n) * 16 + i16) * 128 + ksr * 32 + quad * 8;
            pgh[ks][n] = bld8(Gh + off);
            pgl[ks][n] = bld8(Gl + off);
        }
    }
    // (3) X bulk — consumed by phase 1 (drains under 0a/0b + cross-block TLP)
    f32x4 X0[2][4], X1[2][4];        // [pass][t], 64 VGPRs forced live
    #pragma unroll
    for (int pass = 0; pass < 2; ++pass) {
        int b_loc = 8 * w + pass * 4 + quad;
        const float* xb = x + (size_t)(b0 + b_loc) * 512 + i16 * 8;
        #pragma unroll
        for (int t = 0; t < 4; ++t) {
            X0[pass][t] = ald4(xb + t * 128);
            X1[pass][t] = ald4(xb + t * 128 + 4);
        }
    }

    // ---- Phase 0a: wait y ONLY (16 G + 16 X still in flight), pack to LDS.
    WAITV(32);
    #pragma unroll
    for (int it = 0; it < 2; ++it) {
        float f[8] = {yv0[it][0], yv0[it][1], yv0[it][2], yv0[it][3],
                      yv1[it][0], yv1[it][1], yv1[it][2], yv1[it][3]};
        uint32_t hi[4], lo[4];
        #pragma unroll
        for (int e = 0; e < 4; ++e) {
            unsigned short h0 = f2bf(f[2 * e]), h1 = f2bf(f[2 * e + 1]);
            hi[e] = (uint32_t)h0 | ((uint32_t)h1 << 16);
            lo[e] = (uint32_t)f2bf(f[2 * e] - bf2f(h0)) |
                    ((uint32_t)f2bf(f[2 * e + 1] - bf2f(h1)) << 16);
        }
        int addr = AADDR(rowA[it], gkA[it]);   // rows 0..31 -> [0,8K)
        *(uint4*)(smem + addr)        = make_uint4(hi[0], hi[1], hi[2], hi[3]);
        *(uint4*)(smem + 8192 + addr) = make_uint4(lo[0], lo[1], lo[2], lo[3]);
    }
    BARRIER();          // LDS drained; X queue stays in flight

    // ---- Phase 0b: wait G (X still in flight), g = Y @ G^T.
    WAITV(16);
    {
        f32x4 accg[2][2];    // [sample-tile rt][col-block n]
        #pragma unroll
        for (int rt = 0; rt < 2; ++rt)
            #pragma unroll
            for (int n = 0; n < 2; ++n) accg[rt][n] = (f32x4){0.f, 0.f, 0.f, 0.f};
        #pragma unroll
        for (int ks = 0; ks < 4; ++ks) {
            int ksr = (ks + bid) & 3;
            bf16x8 ah[2], al[2];
            #pragma unroll
            for (int rt = 0; rt < 2; ++rt) {
                int row = 16 * rt + i16;
                int addr = AADDR(row, ksr * 4 + quad);
                ah[rt] = *(const bf16x8*)(smem + addr);
                al[rt] = *(const bf16x8*)(smem + 8192 + addr);
            }
            #pragma unroll
            for (int n = 0; n < 2; ++n) {
                #pragma unroll
                for (int rt = 0; rt < 2; ++rt) {
                    accg[rt][n] = __builtin_amdgcn_mfma_f32_16x16x32_bf16(ah[rt], pgh[ks][n], accg[rt][n], 0, 0, 0);
                    accg[rt][n] = __builtin_amdgcn_mfma_f32_16x16x32_bf16(al[rt], pgh[ks][n], accg[rt][n], 0, 0, 0);
                    accg[rt][n] = __builtin_amdgcn_mfma_f32_16x16x32_bf16(ah[rt], pgl[ks][n], accg[rt][n], 0, 0, 0);
                }
            }
        }
        // C-frag: col = i16 (i offset), row = quad*4+r (sample) -> gbuf fp32
        #pragma unroll
        for (int n = 0; n < 2; ++n) {
            int i = (2 * w + n) * 16 + i16;
            #pragma unroll
            for (int rt = 0; rt < 2; ++rt)
                #pragma unroll
                for (int r = 0; r < 4; ++r)
                    gbufF[(16 * rt + quad * 4 + r) * 128 + i] = accg[rt][n][r];
        }
    }
    BARRIER();          // gbuf visible to all waves; X queue still in flight

    // ---- Phase 1: NOW drain X; dots + softmax + U build.
    WAITV(0);
    #pragma unroll
    for (int pass = 0; pass < 2; ++pass) {
        int b_loc = 8 * w + pass * 4 + quad;
        float4 ga = *(const float4*)(gbufF + b_loc * 128 + i16 * 8);
        float4 gb = *(const float4*)(gbufF + b_loc * 128 + i16 * 8 + 4);
        float xf[4][8];
        float p[4];
        #pragma unroll
        for (int t = 0; t < 4; ++t) {
            #pragma unroll
            for (int e = 0; e < 4; ++e) {
                xf[t][e]     = X0[pass][t][e];
                xf[t][4 + e] = X1[pass][t][e];
            }
            p[t] = xf[t][0] * ga.x + xf[t][1] * ga.y + xf[t][2] * ga.z + xf[t][3] * ga.w
                 + xf[t][4] * gb.x + xf[t][5] * gb.y + xf[t][6] * gb.z + xf[t][7] * gb.w;
        }
        #pragma unroll
        for (int off = 8; off >= 1; off >>= 1) {
            p[0] += __shfl_xor(p[0], off);
            p[1] += __shfl_xor(p[1], off);
            p[2] += __shfl_xor(p[2], off);
            p[3] += __shfl_xor(p[3], off);
        }
        float mx = fmaxf(fmaxf(p[0], p[1]), fmaxf(p[2], p[3]));
        float e0 = __expf(p[0] - mx), e1 = __expf(p[1] - mx);
        float e2 = __expf(p[2] - mx), e3 = __expf(p[3] - mx);
        float inv = 1.f / (e0 + e1 + e2 + e3);
        float w0 = e0 * inv, w1 = e1 * inv, w2 = e2 * inv, w3 = e3 * inv;
        int r0 = 2 * b_loc, r1 = r0 + 1;
        int a0 = AADDR(r0, i16), a1 = AADDR(r1, i16);
        uint32_t eL[4], oL[4], eH[4], oH[4];
        #pragma unroll
        for (int e = 0; e < 4; ++e) {
            int c0 = 2 * e, c1 = 2 * e + 1;
            eL[e] = cvtpk(w0 * xf[0][c0] + w1 * xf[1][c0], w0 * xf[0][c1] + w1 * xf[1][c1]);
            oL[e] = cvtpk(w0 * xf[0][c0] - w1 * xf[1][c0], w0 * xf[0][c1] - w1 * xf[1][c1]);
            eH[e] = cvtpk(w2 * xf[2][c0] + w3 * xf[3][c0], w2 * xf[2][c1] + w3 * xf[3][c1]);
            oH[e] = cvtpk(w2 * xf[2][c0] - w3 * xf[3][c0], w2 * xf[2][c1] - w3 * xf[3][c1]);
        }
        *(uint4*)(smem + a0)         = make_uint4(eL[0], eL[1], eL[2], eL[3]);
        *(uint4*)(smem + a1)         = make_uint4(oL[0], oL[1], oL[2], oL[3]);
        *(uint4*)(smem + 16384 + a0) = make_uint4(eH[0], eH[1], eH[2], eH[3]);
        *(uint4*)(smem + 16384 + a1) = make_uint4(oH[0], oH[1], oH[2], oH[3]);
    }

    // Prefetch phase-2 first-ks B-frags (normal loads; queue is empty now)
    const int ks0b = bid & 7;
    bf16x8 pmh[2];
    {
        int half = ks0b >> 2, kk = ks0b & 3;
        #pragma unroll
        for (int n = 0; n < 2; ++n)
            pmh[n] = *(const bf16x8*)(Mh + ((2 * w + n) * 16 + i16) * 256 + half * 128 + kk * 32 + quad * 8);
    }
    BARRIER();          // phase 2 reads all waves' U rows

    // ---- Phase 2: Z = U(64x256) @ M^T, single-bf16 M, column-split waves.
    f32x4 acc[4][2];   // [row-block rb][col-block n]
    #pragma unroll
    for (int rb = 0; rb < 4; ++rb)
        #pragma unroll
        for (int n = 0; n < 2; ++n) acc[rb][n] = (f32x4){0.f, 0.f, 0.f, 0.f};

    #pragma unroll
    for (int ks = 0; ks < 8; ++ks) {
        int ksr = (ks + bid) & 7;                  // per-block rotation
        int half = ksr >> 2, kk = ksr & 3;
        int base = half << 14;                     // 0 (U-low) or 16384 (U-high)
        int gi = kk * 4 + quad;
        bf16x8 a[4];
        #pragma unroll
        for (int rb = 0; rb < 4; ++rb)
            a[rb] = *(const bf16x8*)(smem + base + AADDR(16 * rb + i16, gi));
        #pragma unroll
        for (int n = 0; n < 2; ++n) {
            bf16x8 bh;
            if (ks == 0) bh = pmh[n];
            else bh = *(const bf16x8*)(Mh + ((2 * w + n) * 16 + i16) * 256 + half * 128 + kk * 32 + quad * 8);
            #pragma unroll
            for (int rb = 0; rb < 4; ++rb)
                acc[rb][n] = __builtin_amdgcn_mfma_f32_16x16x32_bf16(a[rb], bh, acc[rb][n], 0, 0, 0);
        }
    }

    // ---- Epilogue: scale/bias/LeakyReLU, j-contiguous float4 stores
    {
        float* outp = out + (size_t)(bid >> 4) * 131072 + (bid & 15) * 64;
        #pragma unroll
        for (int n = 0; n < 2; ++n) {
            int o = (2 * w + n) * 16 + i16;
            float sc = scale2[o], bi = bias2[o];
            #pragma unroll
            for (int rb = 0; rb < 4; ++rb) {
                int jb = 16 * rb + quad * 4;
                f32x4 a = acc[rb][n];
                float4 r;
                r.x = lrelu(a[0] * sc + bi);
                r.y = lrelu(a[1] * sc + bi);
                r.z = lrelu(a[2] * sc + bi);
                r.w = lrelu(a[3] * sc + bi);
                *(float4*)(outp + (size_t)o * 1024 + jb) = r;
            }
        }
    }
}

extern "C" void kernel_launch(void* const* d_in, const int* in_sizes, int n_in,
                              void* d_out, int out_size, void* d_ws, size_t ws_size,
                              hipStream_t stream)
{
    (void)in_sizes; (void)n_in; (void)out_size; (void)ws_size;
    const float* x        = (const float*)d_in[0];
    const float* y        = (const float*)d_in[1];
    const float* Wq       = (const float*)d_in[2];
    const float* Wk       = (const float*)d_in[3];
    const float* Wv       = (const float*)d_in[4];
    const float* conv_w   = (const float*)d_in[5];
    const float* conv_b   = (const float*)d_in[6];
    const float* bn_gamma = (const float*)d_in[7];
    const float* bn_beta  = (const float*)d_in[8];
    const float* bn_mean  = (const float*)d_in[9];
    const float* bn_var   = (const float*)d_in[10];

    unsigned char* ws = (unsigned char*)d_ws;
    unsigned short* Gh = (unsigned short*)(ws);                // 32 KB
    unsigned short* Gl = (unsigned short*)(ws + 32768);        // 32 KB
    unsigned short* Mh = (unsigned short*)(ws + 65536);        // 64 KB
    float* scale2      = (float*)(ws + 131072);                // 512 B
    float* bias2       = (float*)(ws + 131584);                // 512 B

    hipLaunchKernelGGL(precompute_kernel, dim3(193), dim3(256), 0, stream,
                       Wq, Wk, Wv, conv_w, conv_b, bn_gamma, bn_beta, bn_mean,
                       bn_var, Gh, Gl, Mh, scale2, bias2);
    hipLaunchKernelGGL(fused_kernel, dim3(1024), dim3(256), 0, stream,
                       x, y, Gh, Gl, Mh, scale2, bias2, (float*)d_out);
}